// Round 4
// baseline (799.722 us; speedup 1.0000x reference)
//
#include <hip/hip_runtime.h>
#include <hip/hip_fp16.h>
#include <math.h>

typedef __attribute__((ext_vector_type(8))) short short8b;          // 8 bf16
typedef __attribute__((ext_vector_type(4))) float f32x4;            // MFMA acc
typedef __attribute__((ext_vector_type(4))) unsigned short ushort4b;
typedef __attribute__((ext_vector_type(2))) unsigned short ushort2b;

#define NWIN 8192
#define NT   1024
#define SCALE 0.18257418583505536f   // 30^-0.5

// ---- LDS geometry (element pitches) ----
#define XB_P 200    // xb [64][200] bf16 (row 400B, bank step 4 -> 2-way free)
#define QK_P 200    // qk3 [64][200] bf16: head hh: q @ hh*64, k @ hh*64+32
#define VT_P 72     // vT3 per head [32][72] bf16 (row 144B, step 4)
#define DB_P 68     // dB [64][68] f16
// ---- LDS offsets (bytes) ----
#define OFF_XB  0                 // 25600
#define OFF_QK  25600             // 25600
#define OFF_VT  51200             // 13824  (3 heads x 32*72*2)
#define OFF_DB  65024             // 8704
#define OFF_BPE 73728             // 5120   (bpe [64][20] f32)
#define LDS_BYTES 78848           // 77 KB -> 2 blocks/CU

#define WK 192
#define ATT_P 184                 // global att pitch (bf16); 64*184*2 = 23552 B

__device__ __forceinline__ unsigned short f2bf(float f) {
    union { float f; unsigned int u; } v; v.f = f;
    return (unsigned short)((v.u + 0x7FFFu + ((v.u >> 16) & 1u)) >> 16);
}

// wq2: [2 passes][270 rows][192] bf16, rows ordered m = which*90 + hh*30 + dd
// (pass p covers heads 3p..3p+2).  wp: [192][192] bf16 zero-padded.
__global__ void prep_weights(const float* __restrict__ qkv_w,
                             const float* __restrict__ proj_w,
                             unsigned short* __restrict__ wq2,
                             unsigned short* __restrict__ wp)
{
    const int idx = blockIdx.x * 256 + threadIdx.x;
    if (idx < 2 * 270 * WK) {
        const int p = idx / (270 * WK);
        const int rr = (idx / WK) % 270;
        const int kcol = idx % WK;
        const int which = rr / 90, hh = (rr % 90) / 30, dd = rr % 30;
        const int r_orig = which * 180 + (3 * p + hh) * 30 + dd;
        wq2[idx] = f2bf((kcol < 180) ? qkv_w[r_orig * 180 + kcol] : 0.f);
    }
    const int j = idx - 2 * 270 * WK;
    if (j >= 0 && j < WK * WK) {
        const int r = j / WK, c = j % WK;
        wp[j] = f2bf((r < 180 && c < 180) ? proj_w[r * 180 + c] : 0.f);
    }
}

__global__ void __launch_bounds__(NT, 8)
waga_mfma(const float* __restrict__ x,
          const float* __restrict__ bpe,
          const unsigned short* __restrict__ wq2,
          const unsigned short* __restrict__ wp,
          const float* __restrict__ qkv_b,
          const float* __restrict__ proj_b,
          const float* __restrict__ tau,
          float* __restrict__ out)
{
    extern __shared__ char smem[];
    unsigned short* xb   = (unsigned short*)(smem + OFF_XB);
    unsigned short* qk3  = (unsigned short*)(smem + OFF_QK);
    unsigned short* vT3  = (unsigned short*)(smem + OFF_VT);
    unsigned short* dBs  = (unsigned short*)(smem + OFF_DB);   // f16 bits
    float*          bpes = (float*)(smem + OFF_BPE);

    const int b = blockIdx.x;
    const int t = threadIdx.x;
    const int w = t >> 6;      // wave 0..15
    const int l = t & 63;
    const int lr = l & 15;
    const int g  = l >> 4;

    // att scratch lives in the upper half of this window's out region
    unsigned short* attg = (unsigned short*)((char*)out + (size_t)b * 46080 + 22528);

    // ================= phase 1: pads + staging =================
    if (t < 192) {                     // xb pad cols 180..191
        const int n = t / 3, c = t % 3;
        ushort4b z = {0, 0, 0, 0};
        *reinterpret_cast<ushort4b*>(xb + n * XB_P + 180 + 4 * c) = z;
    } else if (t < 576) {              // qk3 pad cols hh*64+{30,31,62,63}
        const int i = t - 192;
        const int n = i / 6, r = i % 6;
        const int col = (r >> 1) * 64 + (r & 1) * 32 + 30;
        ushort2b z2 = {0, 0};
        *reinterpret_cast<ushort2b*>(qk3 + n * QK_P + col) = z2;
    } else if (t < 640) {              // att global pad cols 180..183
        const int n = t - 576;
        ushort4b z = {0, 0, 0, 0};
        *reinterpret_cast<ushort4b*>(attg + n * ATT_P + 180) = z;
    }
    {
        const float* xw = x + (size_t)b * 11520;
        for (int i = t; i < 64 * 45; i += NT) {
            const int n = i / 45, c4 = i % 45;
            const float4 v = *reinterpret_cast<const float4*>(xw + i * 4);
            ushort4b o;
            o[0] = f2bf(v.x); o[1] = f2bf(v.y); o[2] = f2bf(v.z); o[3] = f2bf(v.w);
            *reinterpret_cast<ushort4b*>(xb + n * XB_P + c4 * 4) = o;
        }
    }
    if (t < 256) {                     // bpe -> LDS f32
        const float4 v = *reinterpret_cast<const float4*>(bpe + (size_t)b * 1024 + t * 4);
        *reinterpret_cast<float4*>(bpes + (t >> 2) * 20 + (t & 3) * 4) = v;
    }
    __syncthreads();

    // ================= phase 2a: dB (f16) =================
    {
        const int ti = t >> 4, tj = t & 15;
        float acc[4] = {0.f, 0.f, 0.f, 0.f};
        #pragma unroll
        for (int k4 = 0; k4 < 4; ++k4) {
            const float4 a = *reinterpret_cast<const float4*>(bpes + ti * 20 + 4 * k4);
            #pragma unroll
            for (int e = 0; e < 4; ++e) {
                const float4 bb = *reinterpret_cast<const float4*>(bpes + (tj + 16 * e) * 20 + 4 * k4);
                float d;
                d = a.x - bb.x; acc[e] += d * d;
                d = a.y - bb.y; acc[e] += d * d;
                d = a.z - bb.z; acc[e] += d * d;
                d = a.w - bb.w; acc[e] += d * d;
            }
        }
        #pragma unroll
        for (int e = 0; e < 4; ++e)
            dBs[ti * DB_P + tj + 16 * e] =
                __half_as_ushort(__float2half_rn(sqrtf(acc[e])));
    }

    // ================= passes: QKV (3 heads) + attention =================
    for (int pass = 0; pass < 2; ++pass) {
        if (pass) __syncthreads();     // attn(p-1) reads done before overwrite

        // ---- QKV: D[chan][tok], A = wq2 rows (global), B = xb rows (LDS) ----
        const unsigned short* wqp = wq2 + (size_t)pass * 270 * WK;
        for (int tile = w; tile < 18; tile += 16) {
            const int seg = tile >> 1;             // 0..8
            const int which = seg / 3, hh = seg % 3;
            const int wbase = which * 90 + hh * 30;     // phys row base in wqp
            const int ddr = ((tile & 1) << 4) + lr;     // this lane's A-row dd
            const bool arow_ok = (ddr < 30);
            const int ddb = ((tile & 1) << 4) + (g << 2); // dd base of D-quad
            // bias per reg (chan = which*180 + (3p+hh)*30 + ddb+i)
            const int bbase = which * 180 + (3 * pass + hh) * 30 + ddb;
            float bias[4];
            #pragma unroll
            for (int i = 0; i < 4; ++i)
                bias[i] = (ddb + i < 30) ? qkv_b[bbase + i] : 0.f;
            f32x4 acc[4];
            #pragma unroll
            for (int mt = 0; mt < 4; ++mt) {
                acc[mt][0] = bias[0]; acc[mt][1] = bias[1];
                acc[mt][2] = bias[2]; acc[mt][3] = bias[3];
            }
            #pragma unroll
            for (int kk = 0; kk < 6; ++kk) {
                short8b af;
                if (arow_ok)
                    af = *reinterpret_cast<const short8b*>(
                        wqp + (size_t)(wbase + ddr) * WK + kk * 32 + g * 8);
                else
                    af = short8b{0,0,0,0,0,0,0,0};
                #pragma unroll
                for (int mt = 0; mt < 4; ++mt) {
                    const short8b bf = *reinterpret_cast<const short8b*>(
                        xb + (mt * 16 + lr) * XB_P + kk * 32 + g * 8);
                    acc[mt] = __builtin_amdgcn_mfma_f32_16x16x32_bf16(af, bf, acc[mt], 0, 0, 0);
                }
            }
            // ---- epilogue: lane holds chans ddb..ddb+3 for tok = mt*16+lr ----
            #pragma unroll
            for (int mt = 0; mt < 4; ++mt) {
                const int tok = mt * 16 + lr;
                float v0 = acc[mt][0], v1 = acc[mt][1], v2 = acc[mt][2], v3 = acc[mt][3];
                if (which == 0) { v0 *= SCALE; v1 *= SCALE; v2 *= SCALE; v3 *= SCALE; }
                if (which < 2) {
                    unsigned short* dst = qk3 + tok * QK_P + hh * 64 + which * 32 + ddb;
                    if (ddb < 28) {
                        ushort4b o = { f2bf(v0), f2bf(v1), f2bf(v2), f2bf(v3) };
                        *reinterpret_cast<ushort4b*>(dst) = o;
                    } else {
                        ushort2b o = { f2bf(v0), f2bf(v1) };
                        *reinterpret_cast<ushort2b*>(dst) = o;
                    }
                } else {
                    // V^T with permuted k-columns: tok j -> col c(j)
                    const int c = (tok & 32) + ((tok >> 2) & 3) * 8 + ((tok >> 4) & 1) * 4 + (tok & 3);
                    unsigned short* base = vT3 + hh * 2304 + c;
                    if (ddb + 0 < 30) base[(ddb + 0) * VT_P] = f2bf(v0);
                    if (ddb + 1 < 30) base[(ddb + 1) * VT_P] = f2bf(v1);
                    if (ddb + 2 < 30) base[(ddb + 2) * VT_P] = f2bf(v2);
                    if (ddb + 3 < 30) base[(ddb + 3) * VT_P] = f2bf(v3);
                }
            }
        }
        __syncthreads();

        // ---- attention: 12 units (hh, mt) over 16 waves ----
        if (w < 12) {
            const int hh = w >> 2, mt = w & 3;
            const int h = 3 * pass + hh;
            const float itau = 1.f / fmaxf(tau[h], 1e-6f);
            // S^T tiles: D[j][tok], C-init = -dB/tau
            f32x4 s[4];
            #pragma unroll
            for (int jt = 0; jt < 4; ++jt)
                #pragma unroll
                for (int i = 0; i < 4; ++i) {
                    const float d = __half2float(__ushort_as_half(
                        dBs[(jt * 16 + g * 4 + i) * DB_P + mt * 16 + lr]));
                    s[jt][i] = -d * itau;
                }
            const short8b qf = *reinterpret_cast<const short8b*>(
                qk3 + (mt * 16 + lr) * QK_P + hh * 64 + g * 8);
            #pragma unroll
            for (int jt = 0; jt < 4; ++jt) {
                const short8b kf = *reinterpret_cast<const short8b*>(
                    qk3 + (jt * 16 + lr) * QK_P + hh * 64 + 32 + g * 8);
                s[jt] = __builtin_amdgcn_mfma_f32_16x16x32_bf16(kf, qf, s[jt], 0, 0, 0);
            }
            // softmax over j: 16 regs per lane + reduce across g-groups
            float mx = s[0][0];
            #pragma unroll
            for (int jt = 0; jt < 4; ++jt)
                #pragma unroll
                for (int i = 0; i < 4; ++i) mx = fmaxf(mx, s[jt][i]);
            mx = fmaxf(mx, __shfl_xor(mx, 16));
            mx = fmaxf(mx, __shfl_xor(mx, 32));
            float sum = 0.f;
            #pragma unroll
            for (int jt = 0; jt < 4; ++jt)
                #pragma unroll
                for (int i = 0; i < 4; ++i) {
                    const float p = __expf(s[jt][i] - mx);
                    s[jt][i] = p; sum += p;
                }
            sum += __shfl_xor(sum, 16);
            sum += __shfl_xor(sum, 32);
            const float inv = 1.f / sum;
            // P regs -> PV B-fragments (slot (g,s) <-> j bijection matches vT cols)
            short8b pb[2];
            #pragma unroll
            for (int ks = 0; ks < 2; ++ks) {
                pb[ks][0] = (short)f2bf(s[2 * ks][0] * inv);
                pb[ks][1] = (short)f2bf(s[2 * ks][1] * inv);
                pb[ks][2] = (short)f2bf(s[2 * ks][2] * inv);
                pb[ks][3] = (short)f2bf(s[2 * ks][3] * inv);
                pb[ks][4] = (short)f2bf(s[2 * ks + 1][0] * inv);
                pb[ks][5] = (short)f2bf(s[2 * ks + 1][1] * inv);
                pb[ks][6] = (short)f2bf(s[2 * ks + 1][2] * inv);
                pb[ks][7] = (short)f2bf(s[2 * ks + 1][3] * inv);
            }
            // PV: D[dd][tok] = mfma(A = vT rows, B = P)
            const int tok = mt * 16 + lr;
            #pragma unroll
            for (int ntd = 0; ntd < 2; ++ntd) {
                f32x4 o = {0.f, 0.f, 0.f, 0.f};
                #pragma unroll
                for (int ks = 0; ks < 2; ++ks) {
                    const short8b va = *reinterpret_cast<const short8b*>(
                        vT3 + hh * 2304 + (ntd * 16 + lr) * VT_P + ks * 32 + g * 8);
                    o = __builtin_amdgcn_mfma_f32_16x16x32_bf16(va, pb[ks], o, 0, 0, 0);
                }
                const int col = h * 30 + ntd * 16 + g * 4;
                unsigned short* dst = attg + tok * ATT_P + col;
                if (ntd == 0 || g < 3) {
                    ushort4b ov = { f2bf(o[0]), f2bf(o[1]), f2bf(o[2]), f2bf(o[3]) };
                    *reinterpret_cast<ushort4b*>(dst) = ov;
                } else {   // cols 28,29 only
                    ushort2b ov = { f2bf(o[0]), f2bf(o[1]) };
                    *reinterpret_cast<ushort2b*>(dst) = ov;
                }
            }
        }
    }
    __syncthreads();   // all att writes drained & visible

    // ================= proj: D[tok][chan], A = att (global), B = wp =================
    f32x4 pacc[3];
    #pragma unroll
    for (int q3 = 0; q3 < 3; ++q3) {
        const int tid = 3 * w + q3;         // 0..47
        const int nt = tid >> 2, mt = tid & 3;
        f32x4 acc = {0.f, 0.f, 0.f, 0.f};
        #pragma unroll
        for (int kk = 0; kk < 6; ++kk) {
            short8b af;
            if (kk == 5 && g == 3)          // cols 184..191 don't exist in att
                af = short8b{0,0,0,0,0,0,0,0};
            else
                af = *reinterpret_cast<const short8b*>(
                    attg + (mt * 16 + lr) * ATT_P + kk * 32 + g * 8);
            const short8b bf = *reinterpret_cast<const short8b*>(
                wp + (nt * 16 + lr) * WK + kk * 32 + g * 8);
            acc = __builtin_amdgcn_mfma_f32_16x16x32_bf16(af, bf, acc, 0, 0, 0);
        }
        pacc[q3] = acc;
    }
    __syncthreads();   // ALL att reads complete before stores overwrite att region
    #pragma unroll
    for (int q3 = 0; q3 < 3; ++q3) {
        const int tid = 3 * w + q3;
        const int nt = tid >> 2, mt = tid & 3;
        const int chan = nt * 16 + lr;
        if (chan < 180) {
            const float pbv = proj_b[chan];
            #pragma unroll
            for (int i = 0; i < 4; ++i)
                out[((size_t)b * 64 + mt * 16 + g * 4 + i) * 180 + chan] = pacc[q3][i] + pbv;
        }
    }
}

extern "C" void kernel_launch(void* const* d_in, const int* in_sizes, int n_in,
                              void* d_out, int out_size, void* d_ws, size_t ws_size,
                              hipStream_t stream) {
    (void)in_sizes; (void)n_in; (void)out_size; (void)ws_size;
    const float* x      = (const float*)d_in[0];
    const float* bpe    = (const float*)d_in[1];
    const float* qkv_w  = (const float*)d_in[2];
    const float* qkv_b  = (const float*)d_in[3];
    const float* proj_w = (const float*)d_in[4];
    const float* proj_b = (const float*)d_in[5];
    const float* tau    = (const float*)d_in[6];

    unsigned short* wq2 = (unsigned short*)d_ws;        // 2*270*192 bf16 = 207360 B
    unsigned short* wp  = wq2 + 2 * 270 * WK;           // 192*192 bf16  = 73728 B

    prep_weights<<<(2 * 270 * WK + WK * WK + 255) / 256, 256, 0, stream>>>(
        qkv_w, proj_w, wq2, wp);

    (void)hipFuncSetAttribute((const void*)waga_mfma,
                              hipFuncAttributeMaxDynamicSharedMemorySize,
                              LDS_BYTES);
    waga_mfma<<<NWIN, NT, LDS_BYTES, stream>>>(x, bpe, wq2, wp, qkv_b, proj_b, tau,
                                               (float*)d_out);
}

// Round 7
// 745.114 us; speedup vs baseline: 1.0733x; 1.0733x over previous
//
#include <hip/hip_runtime.h>
#include <math.h>

typedef __attribute__((ext_vector_type(8))) short short8b;   // 8 bf16 = 4 VGPR
typedef __attribute__((ext_vector_type(4))) float f32x4;     // MFMA acc
typedef __attribute__((ext_vector_type(4))) unsigned short ushort4b;

#define NWIN 8192
#define NT   1024
#define SCALE 0.18257418583505536f   // 30^-0.5

// ---- LDS geometry (element pitches) ----
#define XB_P 200    // xb/att [64][200] bf16; x cols 0..179 (+pad 180..191 zero); att cols h*32+dd (0..191)
#define QK_P 392    // qk [64][392] bf16: head h: q @ h*64+0..29, k @ h*64+32..61 (pads auto-zeroed)
#define VT_P 72     // vT per head [32][72] bf16, rows 30,31 auto-zero, cols = permuted tok
#define DB_P 66     // dB [64][66] f32

// ---- LDS offsets (bytes) ----
#define OFF_XB  0                 // 25600
#define OFF_QK  25600             // 50176
#define OFF_VT  75776             // 27648
#define OFF_DB  103424            // 16896
#define OFF_BPE 120320            // 5120  (bpe [64][20] f32)
#define LDS_BYTES 125440          // 122.5 KB -> 1 block/CU

#define WK 192

__device__ __forceinline__ unsigned short f2bf(float f) {
    union { float f; unsigned int u; } v; v.f = f;
    return (unsigned short)((v.u + 0x7FFFu + ((v.u >> 16) & 1u)) >> 16);
}

// wqr: [540][192] bf16. Row r = seg*30+dd, seg = which*6+hh (which in {q,k,v}), dd 0..29.
// wpr: [192][192] bf16, COLUMNS permuted: k' = hh*32+dd <- proj_w col hh*30+dd (dd>=30 -> 0).
// Total d_ws: 540*192*2 + 192*192*2 = 207360 + 73728 = 281088 B (<= 282624 proven safe in R2).
__global__ void prep_weights(const float* __restrict__ qkv_w,
                             const float* __restrict__ proj_w,
                             unsigned short* __restrict__ wqr,
                             unsigned short* __restrict__ wpr)
{
    const int idx = blockIdx.x * 256 + threadIdx.x;
    if (idx < 540 * WK) {
        const int r = idx / WK, k = idx % WK;
        const int seg = r / 30, dd = r % 30;
        const int which = seg / 6, hh = seg % 6;
        float v = 0.f;
        if (k < 180)
            v = qkv_w[(which * 180 + hh * 30 + dd) * 180 + k];
        wqr[idx] = f2bf(v);
    }
    const int j = idx - 540 * WK;
    if (j >= 0 && j < WK * WK) {
        const int r = j / WK, kp = j % WK;
        const int hh = kp >> 5, dd = kp & 31;
        float v = 0.f;
        if (r < 180 && dd < 30)
            v = proj_w[r * 180 + hh * 30 + dd];
        wpr[j] = f2bf(v);
    }
}

__global__ void __launch_bounds__(NT, 4)
waga_mfma(const float* __restrict__ x,
          const float* __restrict__ bpe,
          const unsigned short* __restrict__ wqr,
          const unsigned short* __restrict__ wpr,
          const float* __restrict__ qkv_b,
          const float* __restrict__ proj_b,
          const float* __restrict__ tau,
          float* __restrict__ out)
{
    extern __shared__ char smem[];
    unsigned short* xb   = (unsigned short*)(smem + OFF_XB);
    unsigned short* qk   = (unsigned short*)(smem + OFF_QK);
    unsigned short* vT   = (unsigned short*)(smem + OFF_VT);
    float*          dBs  = (float*)(smem + OFF_DB);
    float*          bpes = (float*)(smem + OFF_BPE);
    unsigned short* att  = xb;   // att overwrites xb after QKV

    const int b = blockIdx.x;
    const int t = threadIdx.x;
    const int w = t >> 6;      // wave 0..15
    const int l = t & 63;
    const int lr = l & 15;
    const int g  = l >> 4;

    // ================= phase 1: staging =================
    if (t < 192) {                       // xb pad cols 180..191 (read by QKV kk=5)
        const int n = t / 3, c = t % 3;
        *reinterpret_cast<uint2*>(xb + n * XB_P + 180 + 4 * c) = make_uint2(0u, 0u);
    }
    {
        const float* xw = x + (size_t)b * 11520;
        for (int i = t; i < 64 * 45; i += NT) {
            const int n = i / 45, c4 = i % 45;
            const float4 v = *reinterpret_cast<const float4*>(xw + i * 4);
            ushort4b o;
            o[0] = f2bf(v.x); o[1] = f2bf(v.y); o[2] = f2bf(v.z); o[3] = f2bf(v.w);
            *reinterpret_cast<ushort4b*>(xb + n * XB_P + c4 * 4) = o;
        }
    }
    if (t < 256) {                       // bpe -> LDS f32
        const float4 v = *reinterpret_cast<const float4*>(bpe + (size_t)b * 1024 + t * 4);
        *reinterpret_cast<float4*>(bpes + (t >> 2) * 20 + (t & 3) * 4) = v;
    }
    __syncthreads();

    // ================= phase 2a: dB (f32, symmetric) =================
    {
        const int ti = t >> 4, tj = t & 15;
        float acc[4] = {0.f, 0.f, 0.f, 0.f};
        #pragma unroll
        for (int k4 = 0; k4 < 4; ++k4) {
            const float4 a = *reinterpret_cast<const float4*>(bpes + ti * 20 + 4 * k4);
            #pragma unroll
            for (int e = 0; e < 4; ++e) {
                const float4 bb = *reinterpret_cast<const float4*>(bpes + (tj + 16 * e) * 20 + 4 * k4);
                float d;
                d = a.x - bb.x; acc[e] += d * d;
                d = a.y - bb.y; acc[e] += d * d;
                d = a.z - bb.z; acc[e] += d * d;
                d = a.w - bb.w; acc[e] += d * d;
            }
        }
        #pragma unroll
        for (int e = 0; e < 4; ++e)
            dBs[ti * DB_P + tj + 16 * e] = sqrtf(acc[e]);
    }

    // ================= phase 2b: QKV GEMM, D[chan][tok] =================
    // 36 tiles (= 18 segs x 2 halves) over 16 waves; weights prefetched x6.
    // A rows with dd>=30 use a zero fragment -> D rows 30,31 compute zeros that
    // land exactly on the q/k pad cols and vT pad rows (no explicit pad pass).
    for (int tile = w; tile < 36; tile += 16) {
        const int seg = tile >> 1, half = tile & 1;
        const int which = seg / 6, hh = seg % 6;
        const int ddr = half * 16 + lr;             // this lane's A-row dd
        const bool arow_ok = (ddr < 30);
        const unsigned short* wrow = wqr + (size_t)(seg * 30 + (arow_ok ? ddr : 0)) * WK;
        short8b wf[6];
        #pragma unroll
        for (int kk = 0; kk < 6; ++kk) {
            if (arow_ok)
                wf[kk] = *reinterpret_cast<const short8b*>(wrow + kk * 32 + g * 8);
            else
                wf[kk] = short8b{0, 0, 0, 0, 0, 0, 0, 0};
        }
        const int ddb = half * 16 + g * 4;          // chan dd of acc[.]
        const int cbase = which * 180 + hh * 30;
        f32x4 binit;
        #pragma unroll
        for (int i = 0; i < 4; ++i)
            binit[i] = (ddb + i < 30) ? qkv_b[cbase + ddb + i] : 0.f;
        f32x4 acc[4] = {binit, binit, binit, binit};
        short8b xf[4];
        #pragma unroll
        for (int mt = 0; mt < 4; ++mt)
            xf[mt] = *reinterpret_cast<const short8b*>(xb + (mt * 16 + lr) * XB_P + g * 8);
        #pragma unroll
        for (int kk = 0; kk < 6; ++kk) {
            short8b xc[4];
            #pragma unroll
            for (int mt = 0; mt < 4; ++mt) xc[mt] = xf[mt];
            if (kk < 5) {                           // prefetch next kk
                #pragma unroll
                for (int mt = 0; mt < 4; ++mt)
                    xf[mt] = *reinterpret_cast<const short8b*>(
                        xb + (mt * 16 + lr) * XB_P + (kk + 1) * 32 + g * 8);
            }
            #pragma unroll
            for (int mt = 0; mt < 4; ++mt)
                acc[mt] = __builtin_amdgcn_mfma_f32_16x16x32_bf16(wf[kk], xc[mt], acc[mt], 0, 0, 0);
        }
        // epilogue: lane holds chans ddb..ddb+3 for tok = mt*16+lr (no guards:
        // pad rows/cols receive computed zeros)
        #pragma unroll
        for (int mt = 0; mt < 4; ++mt) {
            const int tok = mt * 16 + lr;
            float v0 = acc[mt][0], v1 = acc[mt][1], v2 = acc[mt][2], v3 = acc[mt][3];
            if (which == 0) { v0 *= SCALE; v1 *= SCALE; v2 *= SCALE; v3 *= SCALE; }
            if (which < 2) {
                ushort4b o;
                o[0] = f2bf(v0); o[1] = f2bf(v1); o[2] = f2bf(v2); o[3] = f2bf(v3);
                *reinterpret_cast<ushort4b*>(qk + tok * QK_P + hh * 64 + which * 32 + ddb) = o;
            } else {
                const int c = (tok & 32) + ((tok >> 2) & 3) * 8 + ((tok >> 4) & 1) * 4 + (tok & 3);
                unsigned short* vb = vT + hh * 2304 + ddb * VT_P + c;
                vb[0 * VT_P] = f2bf(v0);
                vb[1 * VT_P] = f2bf(v1);
                vb[2 * VT_P] = f2bf(v2);
                vb[3 * VT_P] = f2bf(v3);
            }
        }
    }
    __syncthreads();

    // ================= phase 3: attention, 24 units (h,mt) over 16 waves =================
    for (int u = w; u < 24; u += 16) {
        const int h = u >> 2, mt = u & 3;
        const unsigned short* qkh = qk + h * 64;
        // prefetch ALL fragments before VALU work
        const short8b qf = *reinterpret_cast<const short8b*>(qkh + (mt * 16 + lr) * QK_P + g * 8);
        short8b kf[4];
        #pragma unroll
        for (int jt = 0; jt < 4; ++jt)
            kf[jt] = *reinterpret_cast<const short8b*>(qkh + (jt * 16 + lr) * QK_P + 32 + g * 8);
        short8b vf[2][2];
        #pragma unroll
        for (int ntd = 0; ntd < 2; ++ntd)
            #pragma unroll
            for (int ks = 0; ks < 2; ++ks)
                vf[ntd][ks] = *reinterpret_cast<const short8b*>(
                    vT + h * 2304 + (ntd * 16 + lr) * VT_P + ks * 32 + g * 8);
        const float itau = 1.f / fmaxf(tau[h], 1e-6f);
        // S^T = mfma(K, Q), C-init = -dB/tau ; D[j][tok], lane: tok=mt*16+lr, j=jt*16+g*4+i
        f32x4 s[4];
        #pragma unroll
        for (int jt = 0; jt < 4; ++jt)
            #pragma unroll
            for (int i = 0; i < 4; ++i)
                s[jt][i] = -itau * dBs[(jt * 16 + g * 4 + i) * DB_P + mt * 16 + lr];
        #pragma unroll
        for (int jt = 0; jt < 4; ++jt)
            s[jt] = __builtin_amdgcn_mfma_f32_16x16x32_bf16(kf[jt], qf, s[jt], 0, 0, 0);
        // softmax over j: 16 regs + 2 shfl steps
        float mx = s[0][0];
        #pragma unroll
        for (int jt = 0; jt < 4; ++jt)
            #pragma unroll
            for (int i = 0; i < 4; ++i) mx = fmaxf(mx, s[jt][i]);
        mx = fmaxf(mx, __shfl_xor(mx, 16));
        mx = fmaxf(mx, __shfl_xor(mx, 32));
        float sum = 0.f;
        #pragma unroll
        for (int jt = 0; jt < 4; ++jt)
            #pragma unroll
            for (int i = 0; i < 4; ++i) {
                const float p = __expf(s[jt][i] - mx);
                s[jt][i] = p; sum += p;
            }
        sum += __shfl_xor(sum, 16);
        sum += __shfl_xor(sum, 32);
        const float inv = 1.f / sum;
        // pack P into PV B-fragments (slot bijection matches vT column permutation)
        short8b pb[2];
        #pragma unroll
        for (int ks = 0; ks < 2; ++ks) {
            pb[ks][0] = (short)f2bf(s[2 * ks][0] * inv);
            pb[ks][1] = (short)f2bf(s[2 * ks][1] * inv);
            pb[ks][2] = (short)f2bf(s[2 * ks][2] * inv);
            pb[ks][3] = (short)f2bf(s[2 * ks][3] * inv);
            pb[ks][4] = (short)f2bf(s[2 * ks + 1][0] * inv);
            pb[ks][5] = (short)f2bf(s[2 * ks + 1][1] * inv);
            pb[ks][6] = (short)f2bf(s[2 * ks + 1][2] * inv);
            pb[ks][7] = (short)f2bf(s[2 * ks + 1][3] * inv);
        }
        // PV: D[dd][tok]; att col = h*32+dd (vT rows 30,31 zero -> pad cols auto-zero)
        const int tok = mt * 16 + lr;
        #pragma unroll
        for (int ntd = 0; ntd < 2; ++ntd) {
            f32x4 o = {0.f, 0.f, 0.f, 0.f};
            o = __builtin_amdgcn_mfma_f32_16x16x32_bf16(vf[ntd][0], pb[0], o, 0, 0, 0);
            o = __builtin_amdgcn_mfma_f32_16x16x32_bf16(vf[ntd][1], pb[1], o, 0, 0, 0);
            ushort4b ov;
            ov[0] = f2bf(o[0]); ov[1] = f2bf(o[1]); ov[2] = f2bf(o[2]); ov[3] = f2bf(o[3]);
            *reinterpret_cast<ushort4b*>(att + tok * XB_P + h * 32 + ntd * 16 + g * 4) = ov;
        }
    }
    __syncthreads();

    // ================= phase 4: proj, D[chan][tok], direct global stores =================
    {
        const int mt = w & 3, ntb = w >> 2;
        short8b attf[6];
        #pragma unroll
        for (int kk = 0; kk < 6; ++kk)
            attf[kk] = *reinterpret_cast<const short8b*>(
                att + (mt * 16 + lr) * XB_P + kk * 32 + g * 8);
        #pragma unroll
        for (int q3 = 0; q3 < 3; ++q3) {
            const int nt = ntb + 4 * q3;
            const unsigned short* wrow = wpr + (size_t)(nt * 16 + lr) * WK;
            short8b wf[6];
            #pragma unroll
            for (int kk = 0; kk < 6; ++kk)
                wf[kk] = *reinterpret_cast<const short8b*>(wrow + kk * 32 + g * 8);
            const int cb = nt * 16 + g * 4;
            f32x4 acc;
            #pragma unroll
            for (int i = 0; i < 4; ++i)
                acc[i] = (cb + i < 180) ? proj_b[cb + i] : 0.f;
            #pragma unroll
            for (int kk = 0; kk < 6; ++kk)
                acc = __builtin_amdgcn_mfma_f32_16x16x32_bf16(wf[kk], attf[kk], acc, 0, 0, 0);
            if (cb < 177) {
                const int tok = mt * 16 + lr;
                *reinterpret_cast<float4*>(out + ((size_t)b * 64 + tok) * 180 + cb) =
                    make_float4(acc[0], acc[1], acc[2], acc[3]);
            }
        }
    }
}

extern "C" void kernel_launch(void* const* d_in, const int* in_sizes, int n_in,
                              void* d_out, int out_size, void* d_ws, size_t ws_size,
                              hipStream_t stream) {
    (void)in_sizes; (void)n_in; (void)out_size; (void)ws_size;
    const float* x      = (const float*)d_in[0];
    const float* bpe    = (const float*)d_in[1];
    const float* qkv_w  = (const float*)d_in[2];
    const float* qkv_b  = (const float*)d_in[3];
    const float* proj_w = (const float*)d_in[4];
    const float* proj_b = (const float*)d_in[5];
    const float* tau    = (const float*)d_in[6];

    unsigned short* wqr = (unsigned short*)d_ws;     // 540*192 bf16 = 207360 B
    unsigned short* wpr = wqr + 540 * WK;            // 192*192 bf16 =  73728 B

    prep_weights<<<(540 * WK + WK * WK + 255) / 256, 256, 0, stream>>>(
        qkv_w, proj_w, wqr, wpr);

    (void)hipFuncSetAttribute((const void*)waga_mfma,
                              hipFuncAttributeMaxDynamicSharedMemorySize,
                              LDS_BYTES);
    waga_mfma<<<NWIN, NT, LDS_BYTES, stream>>>(x, bpe, wqr, wpr, qkv_b, proj_b, tau,
                                               (float*)d_out);
}

// Round 8
// 728.484 us; speedup vs baseline: 1.0978x; 1.0228x over previous
//
#include <hip/hip_runtime.h>
#include <hip/hip_fp16.h>
#include <math.h>

typedef __attribute__((ext_vector_type(8))) short short8b;   // 8 bf16 = 4 VGPR
typedef __attribute__((ext_vector_type(4))) float f32x4;     // MFMA acc
typedef __attribute__((ext_vector_type(4))) unsigned short ushort4b;
typedef __attribute__((ext_vector_type(2))) unsigned short ushort2b;

#define NWIN 8192
#define NT   512
#define SCALE 0.18257418583505536f   // 30^-0.5

// ---- LDS geometry (element pitches) ----
#define XB_P 200    // xb [64][200] bf16; x cols 0..179 + pad 180..191 zero (400B rows, 16B-aligned)
#define QK_P 200    // qk [64][200] bf16 per pass: head hh: q @ hh*64+0..29, k @ hh*64+32..61 (pads auto-zero)
#define VT_P 72     // vT per head [32][72] bf16; rows 30,31 auto-zero; cols = permuted tok
#define DB_P 68     // dB [64][68] f16 (136B rows, 8B-aligned)
#define ATT_P 184   // att in global (d_out upper half): [64][184] bf16, cols h*30+dd, pads 180..183

// ---- LDS offsets (bytes) ----
#define OFF_XB  0                 // 25600
#define OFF_QK  25600             // 25600
#define OFF_VT  51200             // 13824 (3 heads x 32*72*2)
#define OFF_DB  65024             // 8704
#define OFF_BPE 73728             // 5120  (bpe [64][20] f32)
#define LDS_BYTES 78848           // 77 KB -> 2 blocks/CU

#define WK 192

__device__ __forceinline__ unsigned short f2bf(float f) {
    union { float f; unsigned int u; } v; v.f = f;
    return (unsigned short)((v.u + 0x7FFFu + ((v.u >> 16) & 1u)) >> 16);
}

// wqr: [540][192] bf16. Row r = seg*30+dd, seg = which*6+hh_global, dd 0..29. (R7-proven)
// wpr: [192][192] bf16 plain: rows=out-chan (pad rows 180..191 zero), cols=in-chan (pad 180..191 zero).
// d_ws total: 207360 + 73728 = 281088 B (proven-safe envelope).
__global__ void prep_weights(const float* __restrict__ qkv_w,
                             const float* __restrict__ proj_w,
                             unsigned short* __restrict__ wqr,
                             unsigned short* __restrict__ wpr)
{
    const int idx = blockIdx.x * 256 + threadIdx.x;
    if (idx < 540 * WK) {
        const int r = idx / WK, k = idx % WK;
        const int seg = r / 30, dd = r % 30;
        const int which = seg / 6, hh = seg % 6;
        float v = 0.f;
        if (k < 180)
            v = qkv_w[(which * 180 + hh * 30 + dd) * 180 + k];
        wqr[idx] = f2bf(v);
    }
    const int j = idx - 540 * WK;
    if (j >= 0 && j < WK * WK) {
        const int r = j / WK, k = j % WK;
        float v = 0.f;
        if (r < 180 && k < 180)
            v = proj_w[r * 180 + k];
        wpr[j] = f2bf(v);
    }
}

__global__ void __launch_bounds__(NT, 4)
waga_mfma(const float* __restrict__ x,
          const float* __restrict__ bpe,
          const unsigned short* __restrict__ wqr,
          const unsigned short* __restrict__ wpr,
          const float* __restrict__ qkv_b,
          const float* __restrict__ proj_b,
          const float* __restrict__ tau,
          float* __restrict__ out)
{
    extern __shared__ char smem[];
    unsigned short* xb   = (unsigned short*)(smem + OFF_XB);
    unsigned short* qk   = (unsigned short*)(smem + OFF_QK);
    unsigned short* vT   = (unsigned short*)(smem + OFF_VT);
    unsigned short* dBs  = (unsigned short*)(smem + OFF_DB);   // f16 bits
    float*          bpes = (float*)(smem + OFF_BPE);

    const int b = blockIdx.x;
    const int t = threadIdx.x;
    const int w = t >> 6;      // wave 0..7
    const int l = t & 63;
    const int lr = l & 15;
    const int g  = l >> 4;

    // att scratch: upper half of this window's out region (bytes 22528..46080)
    unsigned short* attg = (unsigned short*)((char*)out + (size_t)b * 46080 + 22528);

    // ================= phase 1: staging =================
    if (t < 192) {                       // xb pad cols 180..191
        const int n = t / 3, c = t % 3;
        *reinterpret_cast<uint2*>(xb + n * XB_P + 180 + 4 * c) = make_uint2(0u, 0u);
    } else if (t < 256) {                // attg pad cols 180..183
        const int n = t - 192;
        ushort4b z = {0, 0, 0, 0};
        *reinterpret_cast<ushort4b*>(attg + n * ATT_P + 180) = z;
    }
    {
        const float* xw = x + (size_t)b * 11520;
        for (int i = t; i < 64 * 45; i += NT) {
            const int n = i / 45, c4 = i % 45;
            const float4 v = *reinterpret_cast<const float4*>(xw + i * 4);
            ushort4b o;
            o[0] = f2bf(v.x); o[1] = f2bf(v.y); o[2] = f2bf(v.z); o[3] = f2bf(v.w);
            *reinterpret_cast<ushort4b*>(xb + n * XB_P + c4 * 4) = o;
        }
    }
    if (t < 256) {                       // bpe -> LDS f32
        const float4 v = *reinterpret_cast<const float4*>(bpe + (size_t)b * 1024 + t * 4);
        *reinterpret_cast<float4*>(bpes + (t >> 2) * 20 + (t & 3) * 4) = v;
    }
    __syncthreads();

    // ================= phase 2a: dB (f16, full 64x64) =================
    {
        const int ti = t >> 4, tj = t & 15;   // rows {ti, ti+32}, cols {tj+16e}
        float acc0[4] = {0.f, 0.f, 0.f, 0.f};
        float acc1[4] = {0.f, 0.f, 0.f, 0.f};
        #pragma unroll
        for (int k4 = 0; k4 < 4; ++k4) {
            const float4 a0 = *reinterpret_cast<const float4*>(bpes + ti * 20 + 4 * k4);
            const float4 a1 = *reinterpret_cast<const float4*>(bpes + (ti + 32) * 20 + 4 * k4);
            #pragma unroll
            for (int e = 0; e < 4; ++e) {
                const float4 bb = *reinterpret_cast<const float4*>(bpes + (tj + 16 * e) * 20 + 4 * k4);
                float d;
                d = a0.x - bb.x; acc0[e] += d * d;
                d = a0.y - bb.y; acc0[e] += d * d;
                d = a0.z - bb.z; acc0[e] += d * d;
                d = a0.w - bb.w; acc0[e] += d * d;
                d = a1.x - bb.x; acc1[e] += d * d;
                d = a1.y - bb.y; acc1[e] += d * d;
                d = a1.z - bb.z; acc1[e] += d * d;
                d = a1.w - bb.w; acc1[e] += d * d;
            }
        }
        #pragma unroll
        for (int e = 0; e < 4; ++e) {
            dBs[ti * DB_P + tj + 16 * e] =
                __half_as_ushort(__float2half_rn(sqrtf(acc0[e])));
            dBs[(ti + 32) * DB_P + tj + 16 * e] =
                __half_as_ushort(__float2half_rn(sqrtf(acc1[e])));
        }
    }
    // NOTE: no barrier here — dB is first read in attn, after the QKV barrier.

    // ================= passes: QKV (3 heads) + attention =================
    for (int pass = 0; pass < 2; ++pass) {
        if (pass) __syncthreads();       // attn(pass-1) done reading qk/vT

        // ---- QKV: 18 tiles (9 segs x 2 halves), kk-outer, 2-3 tiles/wave ----
        {
            f32x4 acc[3][4];
            const unsigned short* wrow[3];
            bool has[3], arow_ok[3];
            int whichv[3], hhl[3], halfv[3];
            #pragma unroll
            for (int ti = 0; ti < 3; ++ti) {
                const int tl = w + 8 * ti;
                has[ti] = (tl < 18);
                const int tls = has[ti] ? tl : 0;
                const int segl = tls >> 1;            // 0..8
                halfv[ti] = tls & 1;
                whichv[ti] = segl / 3;
                hhl[ti] = segl % 3;
                const int hg = 3 * pass + hhl[ti];
                const int wseg = whichv[ti] * 6 + hg; // wqr seg
                const int ddr = halfv[ti] * 16 + lr;
                arow_ok[ti] = (ddr < 30);
                wrow[ti] = wqr + (size_t)(wseg * 30 + (arow_ok[ti] ? ddr : 0)) * WK;
                const int ddb = halfv[ti] * 16 + g * 4;
                const int cbase = whichv[ti] * 180 + hg * 30;
                f32x4 binit;
                #pragma unroll
                for (int i = 0; i < 4; ++i)
                    binit[i] = (ddb + i < 30) ? qkv_b[cbase + ddb + i] : 0.f;
                #pragma unroll
                for (int mt = 0; mt < 4; ++mt) acc[ti][mt] = binit;
            }
            #pragma unroll
            for (int kk = 0; kk < 6; ++kk) {
                short8b xf[4];
                #pragma unroll
                for (int mt = 0; mt < 4; ++mt)
                    xf[mt] = *reinterpret_cast<const short8b*>(
                        xb + (mt * 16 + lr) * XB_P + kk * 32 + g * 8);
                #pragma unroll
                for (int ti = 0; ti < 3; ++ti) {
                    if (!has[ti]) continue;
                    short8b wfv;
                    if (arow_ok[ti])
                        wfv = *reinterpret_cast<const short8b*>(wrow[ti] + kk * 32 + g * 8);
                    else
                        wfv = short8b{0, 0, 0, 0, 0, 0, 0, 0};
                    #pragma unroll
                    for (int mt = 0; mt < 4; ++mt)
                        acc[ti][mt] = __builtin_amdgcn_mfma_f32_16x16x32_bf16(
                            wfv, xf[mt], acc[ti][mt], 0, 0, 0);
                }
            }
            // epilogue: lane holds chans ddb..ddb+3 for tok = mt*16+lr.
            // pad rows/cols receive computed zeros (q/k cols 30,31; vT rows 30,31).
            #pragma unroll
            for (int ti = 0; ti < 3; ++ti) {
                if (!has[ti]) continue;
                const int ddb = halfv[ti] * 16 + g * 4;
                #pragma unroll
                for (int mt = 0; mt < 4; ++mt) {
                    const int tok = mt * 16 + lr;
                    float v0 = acc[ti][mt][0], v1 = acc[ti][mt][1];
                    float v2 = acc[ti][mt][2], v3 = acc[ti][mt][3];
                    if (whichv[ti] == 0) { v0 *= SCALE; v1 *= SCALE; v2 *= SCALE; v3 *= SCALE; }
                    if (whichv[ti] < 2) {
                        ushort4b o;
                        o[0] = f2bf(v0); o[1] = f2bf(v1); o[2] = f2bf(v2); o[3] = f2bf(v3);
                        *reinterpret_cast<ushort4b*>(
                            qk + tok * QK_P + hhl[ti] * 64 + whichv[ti] * 32 + ddb) = o;
                    } else {
                        const int c = (tok & 32) + ((tok >> 2) & 3) * 8 + ((tok >> 4) & 1) * 4 + (tok & 3);
                        unsigned short* vb = vT + hhl[ti] * 2304 + ddb * VT_P + c;
                        vb[0 * VT_P] = f2bf(v0);
                        vb[1 * VT_P] = f2bf(v1);
                        vb[2 * VT_P] = f2bf(v2);
                        vb[3 * VT_P] = f2bf(v3);
                    }
                }
            }
        }
        __syncthreads();

        // ---- attention: 12 units (hh, mt) over 8 waves ----
        for (int u = w; u < 12; u += 8) {
            const int hh = u >> 2, mt = u & 3;
            const int h = 3 * pass + hh;
            const unsigned short* qkh = qk + hh * 64;
            // prefetch all fragments
            const short8b qf = *reinterpret_cast<const short8b*>(
                qkh + (mt * 16 + lr) * QK_P + g * 8);
            short8b kf[4];
            #pragma unroll
            for (int jt = 0; jt < 4; ++jt)
                kf[jt] = *reinterpret_cast<const short8b*>(
                    qkh + (jt * 16 + lr) * QK_P + 32 + g * 8);
            short8b vf[2][2];
            #pragma unroll
            for (int ntd = 0; ntd < 2; ++ntd)
                #pragma unroll
                for (int ks = 0; ks < 2; ++ks)
                    vf[ntd][ks] = *reinterpret_cast<const short8b*>(
                        vT + hh * 2304 + (ntd * 16 + lr) * VT_P + ks * 32 + g * 8);
            const float itau = 1.f / fmaxf(tau[h], 1e-6f);
            // S^T = mfma(K, Q), C-init = -dB/tau ; lane: tok=mt*16+lr, j=jt*16+g*4+i
            // dB symmetric -> read row (tok), cols j (contiguous b64)
            f32x4 s[4];
            #pragma unroll
            for (int jt = 0; jt < 4; ++jt) {
                const ushort4b du = *reinterpret_cast<const ushort4b*>(
                    dBs + (mt * 16 + lr) * DB_P + jt * 16 + g * 4);
                #pragma unroll
                for (int i = 0; i < 4; ++i)
                    s[jt][i] = -itau * __half2float(__ushort_as_half(du[i]));
            }
            #pragma unroll
            for (int jt = 0; jt < 4; ++jt)
                s[jt] = __builtin_amdgcn_mfma_f32_16x16x32_bf16(kf[jt], qf, s[jt], 0, 0, 0);
            // softmax over j: 16 regs + 2 shfl steps
            float mx = s[0][0];
            #pragma unroll
            for (int jt = 0; jt < 4; ++jt)
                #pragma unroll
                for (int i = 0; i < 4; ++i) mx = fmaxf(mx, s[jt][i]);
            mx = fmaxf(mx, __shfl_xor(mx, 16));
            mx = fmaxf(mx, __shfl_xor(mx, 32));
            float sum = 0.f;
            #pragma unroll
            for (int jt = 0; jt < 4; ++jt)
                #pragma unroll
                for (int i = 0; i < 4; ++i) {
                    const float p = __expf(s[jt][i] - mx);
                    s[jt][i] = p; sum += p;
                }
            sum += __shfl_xor(sum, 16);
            sum += __shfl_xor(sum, 32);
            const float inv = 1.f / sum;
            // pack P into PV B-fragments (slot bijection matches vT column permutation)
            short8b pb[2];
            #pragma unroll
            for (int ks = 0; ks < 2; ++ks) {
                pb[ks][0] = (short)f2bf(s[2 * ks][0] * inv);
                pb[ks][1] = (short)f2bf(s[2 * ks][1] * inv);
                pb[ks][2] = (short)f2bf(s[2 * ks][2] * inv);
                pb[ks][3] = (short)f2bf(s[2 * ks][3] * inv);
                pb[ks][4] = (short)f2bf(s[2 * ks + 1][0] * inv);
                pb[ks][5] = (short)f2bf(s[2 * ks + 1][1] * inv);
                pb[ks][6] = (short)f2bf(s[2 * ks + 1][2] * inv);
                pb[ks][7] = (short)f2bf(s[2 * ks + 1][3] * inv);
            }
            // PV: D[dd][tok]; att col = h*30+dd (dd 30,31 rows of vT are zero, not stored)
            const int tok = mt * 16 + lr;
            #pragma unroll
            for (int ntd = 0; ntd < 2; ++ntd) {
                f32x4 o = {0.f, 0.f, 0.f, 0.f};
                o = __builtin_amdgcn_mfma_f32_16x16x32_bf16(vf[ntd][0], pb[0], o, 0, 0, 0);
                o = __builtin_amdgcn_mfma_f32_16x16x32_bf16(vf[ntd][1], pb[1], o, 0, 0, 0);
                const int col = h * 30 + ntd * 16 + g * 4;
                unsigned short* dst = attg + tok * ATT_P + col;
                if (ntd == 0 || g < 3) {
                    ushort4b ov;
                    ov[0] = f2bf(o[0]); ov[1] = f2bf(o[1]);
                    ov[2] = f2bf(o[2]); ov[3] = f2bf(o[3]);
                    *reinterpret_cast<ushort4b*>(dst) = ov;
                } else {   // dd 28,29 only
                    ushort2b ov;
                    ov[0] = f2bf(o[0]); ov[1] = f2bf(o[1]);
                    *reinterpret_cast<ushort2b*>(dst) = ov;
                }
            }
        }
    }
    __syncthreads();   // all attg writes drained & visible

    // ================= proj: D[out-chan][tok], 6 tiles/wave sharing attf =================
    {
        const int mt = w & 3;                 // wave's token group
        const int ntb = (w >> 2) * 6;         // nt = ntb..ntb+5
        short8b attf[6];
        #pragma unroll
        for (int kk = 0; kk < 6; ++kk) {
            if (kk == 5 && g == 3)            // att cols 184..191 don't exist
                attf[kk] = short8b{0, 0, 0, 0, 0, 0, 0, 0};
            else
                attf[kk] = *reinterpret_cast<const short8b*>(
                    attg + (mt * 16 + lr) * ATT_P + kk * 32 + g * 8);
        }
        f32x4 pacc[6];
        #pragma unroll
        for (int q6 = 0; q6 < 6; ++q6) {
            const int nt = ntb + q6;
            const unsigned short* wrow = wpr + (size_t)(nt * 16 + lr) * WK;
            const int cb = nt * 16 + g * 4;
            f32x4 acc;
            #pragma unroll
            for (int i = 0; i < 4; ++i)
                acc[i] = (cb + i < 180) ? proj_b[cb + i] : 0.f;
            #pragma unroll
            for (int kk = 0; kk < 6; ++kk) {
                const short8b wf = *reinterpret_cast<const short8b*>(wrow + kk * 32 + g * 8);
                acc = __builtin_amdgcn_mfma_f32_16x16x32_bf16(wf, attf[kk], acc, 0, 0, 0);
            }
            pacc[q6] = acc;
        }
        __syncthreads();   // all attg reads complete before out stores overwrite
        #pragma unroll
        for (int q6 = 0; q6 < 6; ++q6) {
            const int nt = ntb + q6;
            const int cb = nt * 16 + g * 4;
            if (cb < 177) {
                const int tok = mt * 16 + lr;
                *reinterpret_cast<float4*>(out + ((size_t)b * 64 + tok) * 180 + cb) =
                    make_float4(pacc[q6][0], pacc[q6][1], pacc[q6][2], pacc[q6][3]);
            }
        }
    }
}

extern "C" void kernel_launch(void* const* d_in, const int* in_sizes, int n_in,
                              void* d_out, int out_size, void* d_ws, size_t ws_size,
                              hipStream_t stream) {
    (void)in_sizes; (void)n_in; (void)out_size; (void)ws_size;
    const float* x      = (const float*)d_in[0];
    const float* bpe    = (const float*)d_in[1];
    const float* qkv_w  = (const float*)d_in[2];
    const float* qkv_b  = (const float*)d_in[3];
    const float* proj_w = (const float*)d_in[4];
    const float* proj_b = (const float*)d_in[5];
    const float* tau    = (const float*)d_in[6];

    unsigned short* wqr = (unsigned short*)d_ws;     // 540*192 bf16 = 207360 B
    unsigned short* wpr = wqr + 540 * WK;            // 192*192 bf16 =  73728 B

    prep_weights<<<(540 * WK + WK * WK + 255) / 256, 256, 0, stream>>>(
        qkv_w, proj_w, wqr, wpr);

    (void)hipFuncSetAttribute((const void*)waga_mfma,
                              hipFuncAttributeMaxDynamicSharedMemorySize,
                              LDS_BYTES);
    waga_mfma<<<NWIN, NT, LDS_BYTES, stream>>>(x, bpe, wqr, wpr, qkv_b, proj_b, tau,
                                               (float*)d_out);
}